// Round 3
// baseline (84.529 us; speedup 1.0000x reference)
//
#include <hip/hip_runtime.h>

// PillarLayer: fused copy + per-pillar xyz center-of-mass + BEV canvas scatter.
// Strategy (R3): scatter->gather so the canvas is written exactly once,
// full-line coalesced. See R2 gap analysis: direct 4B scatters cost
// ~60-120 MB hidden RMW line traffic.
//   K1 idx_zero:    zero (bs*y_l*x_l) int index map in d_ws (6.9 MB)
//   K2 pillar_fused: copy + reduce + centers[p] (compact) + idx[cell]=p+1
//   K3 canvas_gather: stream canvas as float4, gather centers, full-line writes.

__global__ __launch_bounds__(256) void idx_zero(int4* __restrict__ dst, int n4) {
    int i = blockIdx.x * 256 + threadIdx.x;
    if (i < n4) dst[i] = make_int4(0, 0, 0, 0);
}

__global__ __launch_bounds__(256) void pillar_fused(
    const float4* __restrict__ pillars4,   // P*32 float4 (one per point)
    const int4* __restrict__ coors4,       // P int4 [b,x,y,z]
    const int* __restrict__ npoints,       // P
    const int* __restrict__ xlp,           // scalar x_l
    const int* __restrict__ ylp,           // scalar y_l
    float4* __restrict__ out_pillars4,     // P*32
    float4* __restrict__ out_coors4,       // P
    float* __restrict__ out_np,            // P
    float4* __restrict__ centers,          // P (ws): divided centers, w unused
    int* __restrict__ idx,                 // bs*y_l*x_l (ws): pillar id + 1
    int P)
{
    const int group = blockIdx.x * (blockDim.x >> 5) + (threadIdx.x >> 5);
    const int lane  = threadIdx.x & 31;
    if (group >= P) return;
    const int p = group;

    // Coalesced: 32 lanes x 16B = one full pillar (32 points x 4 ch).
    const float4 v = pillars4[p * 32 + lane];
    out_pillars4[p * 32 + lane] = v;  // passthrough copy

    // Reduce x,y,z over the 32 points (xor masks < 32 stay in-group on wave64).
    float sx = v.x, sy = v.y, sz = v.z;
    #pragma unroll
    for (int m = 16; m >= 1; m >>= 1) {
        sx += __shfl_xor(sx, m);
        sy += __shfl_xor(sy, m);
        sz += __shfl_xor(sz, m);
    }

    if (lane == 0) {
        const int4 c = coors4[p];
        out_coors4[p] = make_float4((float)c.x, (float)c.y, (float)c.z, (float)c.w);

        const int npts = npoints[p];
        out_np[p] = (float)npts;
        const float inv = 1.0f / (float)npts;

        centers[p] = make_float4(sx * inv, sy * inv, sz * inv, 0.f);

        const int x_l = *xlp;
        const int y_l = *ylp;
        // cell within sample b: r = y*x_l + x   (c.x=b, c.y=x, c.z=y)
        idx[c.x * (y_l * x_l) + c.z * x_l + c.y] = p + 1;
    }
}

// One thread per 4 canvas cells of one (b,y,x) slice; writes 3 c-planes.
__global__ __launch_bounds__(256) void canvas_gather(
    const int4* __restrict__ idx4,         // ncells/4
    const float4* __restrict__ centers,    // P
    float4* __restrict__ canvas4,          // bs*3*ncells4
    const int* __restrict__ xlp,
    const int* __restrict__ ylp,
    int ncells4)
{
    int i = blockIdx.x * 256 + threadIdx.x;
    if (i >= ncells4) return;

    const int cs4 = (*xlp * *ylp) >> 2;    // per-sample plane stride in float4
    const int b   = i / cs4;
    const int r4  = i - b * cs4;

    const int4 id = idx4[i];
    float4 wx = make_float4(0.f, 0.f, 0.f, 0.f);
    float4 wy = wx, wz = wx;
    if (id.x > 0) { float4 c = centers[id.x - 1]; wx.x = c.x; wy.x = c.y; wz.x = c.z; }
    if (id.y > 0) { float4 c = centers[id.y - 1]; wx.y = c.x; wy.y = c.y; wz.y = c.z; }
    if (id.z > 0) { float4 c = centers[id.z - 1]; wx.z = c.x; wy.z = c.y; wz.z = c.z; }
    if (id.w > 0) { float4 c = centers[id.w - 1]; wx.w = c.x; wy.w = c.y; wz.w = c.z; }

    const long base = (long)(b * 3) * cs4 + r4;
    canvas4[base]           = wx;
    canvas4[base + cs4]     = wy;
    canvas4[base + 2 * cs4] = wz;
}

// ---- Fallback path (ws too small): zero canvas + direct scatter (R2) ----
__global__ __launch_bounds__(256) void canvas_zero(float4* __restrict__ dst, long n4) {
    long i = (long)blockIdx.x * blockDim.x + threadIdx.x;
    const long stride = (long)gridDim.x * blockDim.x;
    const float4 z = make_float4(0.f, 0.f, 0.f, 0.f);
    for (; i < n4; i += stride) dst[i] = z;
}

__global__ __launch_bounds__(256) void pillar_fused_scatter(
    const float4* __restrict__ pillars4, const int4* __restrict__ coors4,
    const int* __restrict__ npoints, const int* __restrict__ xlp,
    const int* __restrict__ ylp, float4* __restrict__ out_pillars4,
    float4* __restrict__ out_coors4, float* __restrict__ out_np,
    float* __restrict__ canvas, int P)
{
    const int group = blockIdx.x * (blockDim.x >> 5) + (threadIdx.x >> 5);
    const int lane  = threadIdx.x & 31;
    if (group >= P) return;
    const int p = group;
    const float4 v = pillars4[p * 32 + lane];
    out_pillars4[p * 32 + lane] = v;
    float sx = v.x, sy = v.y, sz = v.z;
    #pragma unroll
    for (int m = 16; m >= 1; m >>= 1) {
        sx += __shfl_xor(sx, m);
        sy += __shfl_xor(sy, m);
        sz += __shfl_xor(sz, m);
    }
    if (lane == 0) {
        const int4 c = coors4[p];
        out_coors4[p] = make_float4((float)c.x, (float)c.y, (float)c.z, (float)c.w);
        const int npts = npoints[p];
        out_np[p] = (float)npts;
        const float inv = 1.0f / (float)npts;
        const int x_l = *xlp, y_l = *ylp;
        const long cs = (long)y_l * x_l;
        const long base = (long)c.x * 3l * cs + (long)c.z * x_l + (long)c.y;
        canvas[base] = sx * inv; canvas[base + cs] = sy * inv; canvas[base + 2*cs] = sz * inv;
    }
}

extern "C" void kernel_launch(void* const* d_in, const int* in_sizes, int n_in,
                              void* d_out, int out_size, void* d_ws, size_t ws_size,
                              hipStream_t stream) {
    const float4* pillars4 = (const float4*)d_in[0];
    const int4* coors4     = (const int4*)d_in[1];
    const int* npoints     = (const int*)d_in[2];
    const int* xlp = (const int*)d_in[4];
    const int* ylp = (const int*)d_in[5];

    const int n_pillars = in_sizes[0];   // P*128
    const int n_coors   = in_sizes[1];   // P*4
    const int P         = in_sizes[2];   // pillar count

    float* out           = (float*)d_out;
    float4* out_pillars4 = (float4*)out;
    float* out_coors     = out + n_pillars;
    float* out_np        = out_coors + n_coors;
    float* canvas        = out_np + P;
    const long canvas_elems = (long)out_size - n_pillars - n_coors - P;  // bs*3*ncells
    const long ncells       = canvas_elems / 3;                          // bs*y_l*x_l

    const size_t ws_need = (size_t)P * 16 + (size_t)ncells * 4;
    const int groups_per_block = 256 / 32;  // 8 pillars per block
    const int blocks = (P + groups_per_block - 1) / groups_per_block;

    if (ws_size >= ws_need && (ncells & 3) == 0) {
        float4* centers = (float4*)d_ws;
        int*    idx     = (int*)((char*)d_ws + (size_t)P * 16);
        const int ncells4 = (int)(ncells >> 2);

        idx_zero<<<(ncells4 + 255) / 256, 256, 0, stream>>>((int4*)idx, ncells4);
        pillar_fused<<<blocks, 256, 0, stream>>>(
            pillars4, coors4, npoints, xlp, ylp,
            out_pillars4, (float4*)out_coors, out_np, centers, idx, P);
        canvas_gather<<<(ncells4 + 255) / 256, 256, 0, stream>>>(
            (const int4*)idx, centers, (float4*)canvas, xlp, ylp, ncells4);
    } else {
        const long n4 = canvas_elems >> 2;
        canvas_zero<<<(int)((n4 + 255) / 256), 256, 0, stream>>>((float4*)canvas, n4);
        pillar_fused_scatter<<<blocks, 256, 0, stream>>>(
            pillars4, coors4, npoints, xlp, ylp,
            out_pillars4, (float4*)out_coors, out_np, canvas, P);
    }
}

// Round 5
// 76.659 us; speedup vs baseline: 1.1027x; 1.1027x over previous
//
#include <hip/hip_runtime.h>

// PillarLayer: fused copy + per-pillar xyz center-of-mass + BEV canvas scatter.
//
// R5 = R4 with the compile fix: __builtin_nontemporal_* requires a NATIVE
// vector type (clang ext_vector), not HIP_vector_type<float,4>.
//
//   K1 canvas_zero:   zero the 20.6 MB canvas with NORMAL (cache-allocating)
//                     stores so the lines stay resident in L3.
//   K2 pillar_fused:  copy pillars with NON-TEMPORAL loads/stores (327 MB
//                     streamed without evicting L3), reduce xyz, scatter the
//                     3 center floats per pillar into L3-resident lines.
//
// Inputs: d_in[0] pillars f32 (P,32,4); d_in[1] coors int32 (P,4) [b,x,y,z];
//         d_in[2] npoints int32 (P); d_in[3] bs; d_in[4] x_l; d_in[5] y_l.
// Output (concat f32): pillars copy | coors as f32 | npoints as f32 |
//         canvas (bs,3,y_l,x_l) with canvas[b][c][y][x] = center_c or 0.

typedef float vfloat4 __attribute__((ext_vector_type(4)));

__global__ __launch_bounds__(256) void canvas_zero(float4* __restrict__ dst, long n4) {
    long i = (long)blockIdx.x * blockDim.x + threadIdx.x;
    const long stride = (long)gridDim.x * blockDim.x;
    const float4 z = make_float4(0.f, 0.f, 0.f, 0.f);
    for (; i < n4; i += stride) dst[i] = z;   // normal stores: want L3 residency
}

__global__ __launch_bounds__(256) void pillar_fused(
    const vfloat4* __restrict__ pillars4,  // P*32 vfloat4 (one per point)
    const int4* __restrict__ coors4,       // P int4 [b,x,y,z]
    const int* __restrict__ npoints,       // P
    const int* __restrict__ xlp,           // scalar x_l
    const int* __restrict__ ylp,           // scalar y_l
    vfloat4* __restrict__ out_pillars4,    // P*32
    float4* __restrict__ out_coors4,       // P
    float* __restrict__ out_np,            // P
    float* __restrict__ canvas,            // bs*3*y_l*x_l
    int P)
{
    const int group = blockIdx.x * (blockDim.x >> 5) + (threadIdx.x >> 5);
    const int lane  = threadIdx.x & 31;
    if (group >= P) return;
    const int p = group;

    // Coalesced: 32 lanes x 16B = one full pillar; wave64 covers 1KB contig.
    // Non-temporal: stream 327 MB without allocating in L2/L3 so the zeroed
    // canvas stays cache-resident for the scatter below.
    const vfloat4 v = __builtin_nontemporal_load(&pillars4[p * 32 + lane]);
    __builtin_nontemporal_store(v, &out_pillars4[p * 32 + lane]);

    // Reduce x,y,z over the 32 points (xor masks < 32 stay in-group on wave64).
    float sx = v.x, sy = v.y, sz = v.z;
    #pragma unroll
    for (int m = 16; m >= 1; m >>= 1) {
        sx += __shfl_xor(sx, m);
        sy += __shfl_xor(sy, m);
        sz += __shfl_xor(sz, m);
    }

    if (lane < 3) {
        // Same-address loads across lanes 0-2 coalesce to one request.
        const int4 c  = coors4[p];
        const int npts = npoints[p];
        const float s = (lane == 0) ? sx : (lane == 1) ? sy : sz;
        const float val = s / (float)npts;

        const int x_l = *xlp;
        const int y_l = *ylp;
        const long cs   = (long)y_l * (long)x_l;           // plane stride
        const long base = (long)c.x * 3l * cs + (long)c.z * (long)x_l + (long)c.y;
        canvas[base + (long)lane * cs] = val;              // 3 planes via 3 lanes

        if (lane == 0) {
            out_coors4[p] = make_float4((float)c.x, (float)c.y, (float)c.z, (float)c.w);
            out_np[p] = (float)npts;
        }
    }
}

extern "C" void kernel_launch(void* const* d_in, const int* in_sizes, int n_in,
                              void* d_out, int out_size, void* d_ws, size_t ws_size,
                              hipStream_t stream) {
    const vfloat4* pillars4 = (const vfloat4*)d_in[0];
    const int4* coors4      = (const int4*)d_in[1];
    const int* npoints      = (const int*)d_in[2];
    const int* xlp = (const int*)d_in[4];
    const int* ylp = (const int*)d_in[5];

    const int n_pillars = in_sizes[0];   // P*128
    const int n_coors   = in_sizes[1];   // P*4
    const int P         = in_sizes[2];   // pillar count

    float* out            = (float*)d_out;
    vfloat4* out_pillars4 = (vfloat4*)out;
    float* out_coors      = out + n_pillars;
    float* out_np         = out_coors + n_coors;
    float* canvas         = out_np + P;
    const long canvas_elems = (long)out_size - n_pillars - n_coors - P;  // bs*3*y_l*x_l

    // K1: zero canvas (cacheable stores -> L3 resident for the scatter RMW).
    const long n4 = canvas_elems >> 2;   // canvas start is 16B-aligned (P*133 % 4 == 0 here)
    canvas_zero<<<(int)((n4 + 255) / 256), 256, 0, stream>>>((float4*)canvas, n4);

    // K2: fused copy + reduce + scatter.
    const int groups_per_block = 256 / 32;  // 8 pillars per block
    const int blocks = (P + groups_per_block - 1) / groups_per_block;
    pillar_fused<<<blocks, 256, 0, stream>>>(
        pillars4, coors4, npoints, xlp, ylp,
        out_pillars4, (float4*)out_coors, out_np, canvas, P);
}